// Round 4
// baseline (352.992 us; speedup 1.0000x reference)
//
#include <hip/hip_runtime.h>
#include <hip/hip_bf16.h>

#define TOKENS 2048
#define DIM 512
#define NEXP 16
#define HID 2048
#define CAP 320                 /* rows per expert (mean 256, +4 sigma margin) */
#define NTPE (CAP / 64)         /* 5 m-tiles per expert */
#define MTILES (NEXP * NTPE)    /* 80 */
#define NROWS (NEXP * CAP)      /* 5120 */

typedef unsigned short ushort_t;
typedef __attribute__((ext_vector_type(8))) __bf16 bf16x8;
typedef __attribute__((ext_vector_type(4))) float f32x4;

// workspace byte offsets (total 90,260,480)
#define OFF_CNT 0
#define OFF_LTOK 1024
#define OFF_LW 21504
#define OFF_S1 41984
#define OFF_S2 62464
#define OFF_XBF 82944        /* 2048*512*2 = 2,097,152 -> ends 2,180,096 */
#define OFF_H 2180096        /* 5120*2048*2 = 20,971,520 -> ends 23,151,616 */
#define OFF_W1T 23151616     /* 33,554,432 -> ends 56,706,048 */
#define OFF_W2T 56706048     /* 33,554,432 -> ends 90,260,480 */

__device__ __forceinline__ ushort_t f2b(float f) {
  __bf16 b = (__bf16)f;
  return __builtin_bit_cast(unsigned short, b);
}
__device__ __forceinline__ float b2f(ushort_t u) {
  return __builtin_bit_cast(float, (unsigned)u << 16);
}

// ---------- weight convert+transpose, LDS-free ------------------------------
// Each thread: 32 coalesced strided fp32 reads -> 64B contiguous bf16 write.
// src[E][K][N] f32 -> dst[E][N][K] bf16, for both W1 and W2.
__global__ __launch_bounds__(256) void wconv_k(
    const float* __restrict__ W1, const float* __restrict__ W2,
    ushort_t* __restrict__ W1t, ushort_t* __restrict__ W2t,
    int* __restrict__ counts) {
  if (blockIdx.x == 0 && threadIdx.x < NEXP) counts[threadIdx.x] = 0;
  unsigned gid = blockIdx.x * 256 + threadIdx.x;
  const float* src;
  ushort_t* dst;
  int K, N, n, kc, e;
  if (gid < 524288u) {  // W1: K=512, N=2048; 16kc x 2048n x 16e
    src = W1; dst = W1t; K = DIM; N = HID;
    n = gid & 2047; kc = (gid >> 11) & 15; e = gid >> 15;
  } else {              // W2: K=2048, N=512; 64kc x 512n x 16e
    gid -= 524288u;
    src = W2; dst = W2t; K = HID; N = DIM;
    n = gid & 511; kc = (gid >> 9) & 63; e = gid >> 15;
  }
  const float* sp = src + ((size_t)e * K + kc * 32) * N + n;
  union { ushort_t u[32]; uint4 q[4]; } o;
#pragma unroll
  for (int j = 0; j < 32; j++) o.u[j] = f2b(sp[(size_t)j * N]);
  ushort_t* dp = dst + ((size_t)e * N + n) * K + kc * 32;
#pragma unroll
  for (int i = 0; i < 4; i++) *(uint4*)(dp + i * 8) = o.q[i];
}

// ---------------- router: logits, top-2, softmax, slot assignment -----------
__global__ __launch_bounds__(256) void router_k(
    const float* __restrict__ x, const float* __restrict__ Wg,
    ushort_t* __restrict__ xbf, int* __restrict__ counts,
    int* __restrict__ ltok, float* __restrict__ lw,
    float* __restrict__ s1, float* __restrict__ s2, float* __restrict__ out) {
  int t = threadIdx.x;
  {  // zero out (4MB over 64 blocks)
    float4 z = {0.f, 0.f, 0.f, 0.f};
    float4* o4 = (float4*)out + blockIdx.x * 4096 + t;
#pragma unroll
    for (int i = 0; i < 16; i++) o4[i * 256] = z;
  }
  {  // zero s1/s2
    int idx = blockIdx.x * 256 + t;
    if (idx < NROWS) { s1[idx] = 0.f; s2[idx] = 0.f; }
  }

  __shared__ float xs[4][512];
  __shared__ float lg[4][16];
  __shared__ int lcnt[NEXP];
  __shared__ int ltoks[NEXP][64];
  __shared__ float lws[NEXP][64];
  __shared__ int base_s[NEXP];

  if (t < NEXP) lcnt[t] = 0;
  __syncthreads();

  int lane = t & 63, w = t >> 6;
  int dq = lane >> 2, e4 = lane & 3;
  const float* wgp = Wg + dq * NEXP + e4 * 4;

  for (int it = 0; it < 8; it++) {
    int tok = blockIdx.x * 32 + w * 8 + it;
    const float* xr = x + (size_t)tok * DIM + lane * 8;
    float4 xa = *(const float4*)xr;
    float4 xb = *(const float4*)(xr + 4);
    union { ushort_t u[8]; uint4 v; } pk;
    pk.u[0] = f2b(xa.x); pk.u[1] = f2b(xa.y); pk.u[2] = f2b(xa.z); pk.u[3] = f2b(xa.w);
    pk.u[4] = f2b(xb.x); pk.u[5] = f2b(xb.y); pk.u[6] = f2b(xb.z); pk.u[7] = f2b(xb.w);
    *(uint4*)(xbf + (size_t)tok * DIM + lane * 8) = pk.v;
    *(float4*)&xs[w][lane * 8] = xa;
    *(float4*)&xs[w][lane * 8 + 4] = xb;

    float4 a = {0.f, 0.f, 0.f, 0.f};
#pragma unroll
    for (int kk = 0; kk < 32; kk++) {
      float xv = xs[w][kk * 16 + dq];
      float4 g = *(const float4*)(wgp + kk * 16 * NEXP);
      a.x += xv * g.x; a.y += xv * g.y; a.z += xv * g.z; a.w += xv * g.w;
    }
#pragma unroll
    for (int off = 32; off >= 4; off >>= 1) {
      a.x += __shfl_down(a.x, off);
      a.y += __shfl_down(a.y, off);
      a.z += __shfl_down(a.z, off);
      a.w += __shfl_down(a.w, off);
    }
    if (lane < 4) *(float4*)&lg[w][lane * 4] = a;
    if (lane == 0) {
      int i0 = 0;
      float v0 = lg[w][0];
#pragma unroll
      for (int e = 1; e < NEXP; e++)
        if (lg[w][e] > v0) { v0 = lg[w][e]; i0 = e; }
      int i1 = -1;
      float v1 = -3.4e38f;
#pragma unroll
      for (int e = 0; e < NEXP; e++)
        if (e != i0 && lg[w][e] > v1) { v1 = lg[w][e]; i1 = e; }
      float ex = __expf(v1 - v0);
      float w0 = 1.f / (1.f + ex);
      int p0 = atomicAdd(&lcnt[i0], 1);
      ltoks[i0][p0] = tok;
      lws[i0][p0] = w0;
      int p1 = atomicAdd(&lcnt[i1], 1);
      ltoks[i1][p1] = tok;
      lws[i1][p1] = ex / (1.f + ex);
    }
  }
  __syncthreads();
  if (t < NEXP) base_s[t] = atomicAdd(&counts[t], lcnt[t]);
  __syncthreads();
  int e = t >> 4, i0 = t & 15;
  int n = lcnt[e], b = base_s[e];
  for (int i = i0; i < n; i += 16) {
    int slot = b + i;
    if (slot < CAP) {
      ltok[e * CAP + slot] = ltoks[e][i];
      lw[e * CAP + slot] = lws[e][i];
    }
  }
}

// ---------------- GEMM1: h = silu(x @ W1 + b1), no LDS, fused stats ---------
// W1t: [E][H][D] bf16 (k=D contiguous). A fragments loaded direct from xbf.
__global__ __launch_bounds__(256) void ffn1_k(
    const ushort_t* __restrict__ W1t, const float* __restrict__ b1,
    const int* __restrict__ counts, const int* __restrict__ ltok,
    const ushort_t* __restrict__ xbf, ushort_t* __restrict__ hbuf,
    float* __restrict__ s1, float* __restrict__ s2) {
  int e = blockIdx.x / NTPE, mt = blockIdx.x % NTPE;
  int cnt = counts[e];
  if (cnt - mt * 64 <= 0) return;
  int row0 = e * CAP + mt * 64;
  int h0 = blockIdx.y * 128;

  int t = threadIdx.x;
  int lane = t & 63, wave = t >> 6;
  int quad = lane >> 4, l16 = lane & 15;

  const ushort_t* ap[4];
#pragma unroll
  for (int mb = 0; mb < 4; mb++) {
    int gr = mt * 64 + mb * 16 + l16;
    int tk = (gr < cnt) ? ltok[row0 + mb * 16 + l16] : 0;
    ap[mb] = xbf + (size_t)tk * DIM + quad * 8;
  }

  int ncol = h0 + wave * 32 + l16;
  const ushort_t* bb = W1t + ((size_t)e * HID + ncol) * DIM + quad * 8;

  f32x4 acc[4][2];
#pragma unroll
  for (int a = 0; a < 4; a++)
#pragma unroll
    for (int b = 0; b < 2; b++) acc[a][b] = {0.f, 0.f, 0.f, 0.f};

#pragma unroll 4
  for (int ks = 0; ks < DIM / 32; ks++) {
    int kc = ks * 32;
    bf16x8 bfr0 = *(const bf16x8*)(bb + kc);
    bf16x8 bfr1 = *(const bf16x8*)(bb + (size_t)16 * DIM + kc);
    bf16x8 af[4];
#pragma unroll
    for (int mb = 0; mb < 4; mb++) af[mb] = *(const bf16x8*)(ap[mb] + kc);
#pragma unroll
    for (int mb = 0; mb < 4; mb++) {
      acc[mb][0] = __builtin_amdgcn_mfma_f32_16x16x32_bf16(af[mb], bfr0, acc[mb][0], 0, 0, 0);
      acc[mb][1] = __builtin_amdgcn_mfma_f32_16x16x32_bf16(af[mb], bfr1, acc[mb][1], 0, 0, 0);
    }
  }

  float bia0 = b1[e * HID + ncol];
  float bia1 = b1[e * HID + ncol + 16];
#pragma unroll
  for (int mb = 0; mb < 4; mb++) {
#pragma unroll
    for (int i = 0; i < 4; i++) {
      int m = mb * 16 + quad * 4 + i;
      size_t rowg = (size_t)(row0 + m);
      float v0 = acc[mb][0][i] + bia0;
      v0 = v0 / (1.f + __expf(-v0));
      float v1 = acc[mb][1][i] + bia1;
      v1 = v1 / (1.f + __expf(-v1));
      hbuf[rowg * HID + ncol] = f2b(v0);
      hbuf[rowg * HID + ncol + 16] = f2b(v1);
      float ps = v0 + v1, qs = v0 * v0 + v1 * v1;
      ps += __shfl_down(ps, 8); qs += __shfl_down(qs, 8);
      ps += __shfl_down(ps, 4); qs += __shfl_down(qs, 4);
      ps += __shfl_down(ps, 2); qs += __shfl_down(qs, 2);
      ps += __shfl_down(ps, 1); qs += __shfl_down(qs, 1);
      if (l16 == 0) {
        atomicAdd(&s1[rowg], ps);
        atomicAdd(&s2[rowg], qs);
      }
    }
  }
}

// ---------------- normalize hbuf rows in place (LayerNorm) ------------------
__global__ __launch_bounds__(256) void norm_k(
    const int* __restrict__ counts, const float* __restrict__ s1,
    const float* __restrict__ s2, const float* __restrict__ lng,
    const float* __restrict__ lnb, ushort_t* __restrict__ hbuf) {
  int row = blockIdx.x;
  int e = row / CAP;
  if ((row % CAP) >= counts[e]) return;
  float mu = s1[row] * (1.f / HID);
  float var = s2[row] * (1.f / HID) - mu * mu;
  float rs = rsqrtf(var + 1e-5f);
  int t = threadIdx.x;
  ushort_t* hp = hbuf + (size_t)row * HID + t * 8;
  const float* gp = lng + (size_t)e * HID + t * 8;
  const float* cp = lnb + (size_t)e * HID + t * 8;
  union { uint4 v; ushort_t u[8]; } hv;
  hv.v = *(const uint4*)hp;
  float4 g0 = *(const float4*)gp;
  float4 g1 = *(const float4*)(gp + 4);
  float4 c0 = *(const float4*)cp;
  float4 c1 = *(const float4*)(cp + 4);
  float gs[8] = {g0.x, g0.y, g0.z, g0.w, g1.x, g1.y, g1.z, g1.w};
  float cs[8] = {c0.x, c0.y, c0.z, c0.w, c1.x, c1.y, c1.z, c1.w};
  union { ushort_t u[8]; uint4 v; } pk;
#pragma unroll
  for (int j = 0; j < 8; j++) {
    float f = (b2f(hv.u[j]) - mu) * rs;
    pk.u[j] = f2b(f * gs[j] + cs[j]);
  }
  *(uint4*)hp = pk.v;
}

// ---------------- GEMM2: out[t] += w * (hn @ W2 + b2), no LDS ---------------
// W2t: [E][D][H] bf16 (k=H contiguous). K split in 2 via blockIdx.z.
__global__ __launch_bounds__(256) void ffn2_k(
    const ushort_t* __restrict__ W2t, const float* __restrict__ b2,
    const int* __restrict__ counts, const int* __restrict__ ltok,
    const float* __restrict__ lw, const ushort_t* __restrict__ hbuf,
    float* __restrict__ out) {
  int e = blockIdx.x / NTPE, mt = blockIdx.x % NTPE;
  int cnt = counts[e];
  int valid = cnt - mt * 64;
  if (valid <= 0) return;
  valid = valid > 64 ? 64 : valid;
  int row0 = e * CAP + mt * 64;
  int n0 = blockIdx.y * 128;
  int kbeg = blockIdx.z * (HID / 2);

  int t = threadIdx.x;
  int lane = t & 63, wave = t >> 6;
  int quad = lane >> 4, l16 = lane & 15;

  const ushort_t* ap[4];
#pragma unroll
  for (int mb = 0; mb < 4; mb++)
    ap[mb] = hbuf + (size_t)(row0 + mb * 16 + l16) * HID + kbeg + quad * 8;

  int ncol = n0 + wave * 32 + l16;
  const ushort_t* bb = W2t + ((size_t)e * DIM + ncol) * HID + kbeg + quad * 8;

  f32x4 acc[4][2];
#pragma unroll
  for (int a = 0; a < 4; a++)
#pragma unroll
    for (int b = 0; b < 2; b++) acc[a][b] = {0.f, 0.f, 0.f, 0.f};

#pragma unroll 8
  for (int ks = 0; ks < (HID / 2) / 32; ks++) {
    int kc = ks * 32;
    bf16x8 bfr0 = *(const bf16x8*)(bb + kc);
    bf16x8 bfr1 = *(const bf16x8*)(bb + (size_t)16 * HID + kc);
    bf16x8 af[4];
#pragma unroll
    for (int mb = 0; mb < 4; mb++) af[mb] = *(const bf16x8*)(ap[mb] + kc);
#pragma unroll
    for (int mb = 0; mb < 4; mb++) {
      acc[mb][0] = __builtin_amdgcn_mfma_f32_16x16x32_bf16(af[mb], bfr0, acc[mb][0], 0, 0, 0);
      acc[mb][1] = __builtin_amdgcn_mfma_f32_16x16x32_bf16(af[mb], bfr1, acc[mb][1], 0, 0, 0);
    }
  }

  bool addb = (blockIdx.z == 0);
#pragma unroll
  for (int mb = 0; mb < 4; mb++) {
#pragma unroll
    for (int i = 0; i < 4; i++) {
      int m = mb * 16 + quad * 4 + i;
      if (m < valid) {
        int tok = ltok[row0 + m];
        float w = lw[row0 + m];
#pragma unroll
        for (int nb = 0; nb < 2; nb++) {
          int n = ncol + nb * 16;
          float v = acc[mb][nb][i] + (addb ? b2[e * DIM + n] : 0.f);
          atomicAdd(out + (size_t)tok * DIM + n, w * v);
        }
      }
    }
  }
}

extern "C" void kernel_launch(void* const* d_in, const int* in_sizes, int n_in,
                              void* d_out, int out_size, void* d_ws, size_t ws_size,
                              hipStream_t stream) {
  const float* x = (const float*)d_in[0];
  const float* Wg = (const float*)d_in[1];
  const float* W1 = (const float*)d_in[2];
  const float* b1 = (const float*)d_in[3];
  const float* lng = (const float*)d_in[4];
  const float* lnb = (const float*)d_in[5];
  const float* W2 = (const float*)d_in[6];
  const float* b2 = (const float*)d_in[7];
  float* out = (float*)d_out;

  char* ws = (char*)d_ws;
  int* counts = (int*)(ws + OFF_CNT);
  int* ltok = (int*)(ws + OFF_LTOK);
  float* lw = (float*)(ws + OFF_LW);
  float* s1 = (float*)(ws + OFF_S1);
  float* s2 = (float*)(ws + OFF_S2);
  ushort_t* xbf = (ushort_t*)(ws + OFF_XBF);
  ushort_t* hbuf = (ushort_t*)(ws + OFF_H);
  ushort_t* W1t = (ushort_t*)(ws + OFF_W1T);
  ushort_t* W2t = (ushort_t*)(ws + OFF_W2T);

  wconv_k<<<4096, 256, 0, stream>>>(W1, W2, W1t, W2t, counts);
  router_k<<<64, 256, 0, stream>>>(x, Wg, xbf, counts, ltok, lw, s1, s2, out);
  ffn1_k<<<dim3(MTILES, HID / 128), 256, 0, stream>>>(W1t, b1, counts, ltok, xbf, hbuf, s1, s2);
  norm_k<<<NROWS, 256, 0, stream>>>(counts, s1, s2, lng, lnb, hbuf);
  ffn2_k<<<dim3(MTILES, DIM / 128, 2), 256, 0, stream>>>(W2t, b2, counts, ltok, lw, hbuf, out);
}

// Round 6
// 286.446 us; speedup vs baseline: 1.2323x; 1.2323x over previous
//
#include <hip/hip_runtime.h>
#include <hip/hip_bf16.h>

#define TOKENS 2048
#define DIM 512
#define NEXP 16
#define HID 2048
#define CAP 320                 /* rows per expert (mean 256, +4 sigma margin) */
#define NTPE (CAP / 64)         /* 5 m-tiles per expert */
#define MTILES (NEXP * NTPE)    /* 80 */
#define NROWS (NEXP * CAP)      /* 5120 */

typedef unsigned short ushort_t;
typedef __attribute__((ext_vector_type(8))) __bf16 bf16x8;
typedef __attribute__((ext_vector_type(4))) float f32x4;

// workspace byte offsets (total 90,260,480)
#define OFF_CNT 0
#define OFF_LTOK 1024
#define OFF_LW 21504
#define OFF_S1 41984
#define OFF_S2 62464
#define OFF_XBF 82944        /* 2048*512*2 = 2,097,152 -> ends 2,180,096 */
#define OFF_H 2180096        /* 5120*2048*2 = 20,971,520 -> ends 23,151,616 */
#define OFF_W1T 23151616     /* 33,554,432 -> ends 56,706,048 */
#define OFF_W2T 56706048     /* 33,554,432 -> ends 90,260,480 */

__device__ __forceinline__ ushort_t f2b(float f) {
  __bf16 b = (__bf16)f;
  return __builtin_bit_cast(unsigned short, b);
}
__device__ __forceinline__ float b2f(ushort_t u) {
  return __builtin_bit_cast(float, (unsigned)u << 16);
}

// ---------- weight convert+transpose, LDS-free ------------------------------
__global__ __launch_bounds__(256) void wconv_k(
    const float* __restrict__ W1, const float* __restrict__ W2,
    ushort_t* __restrict__ W1t, ushort_t* __restrict__ W2t,
    int* __restrict__ counts) {
  if (blockIdx.x == 0 && threadIdx.x < NEXP) counts[threadIdx.x] = 0;
  unsigned gid = blockIdx.x * 256 + threadIdx.x;
  const float* src;
  ushort_t* dst;
  int K, N, n, kc, e;
  if (gid < 524288u) {  // W1: K=512, N=2048
    src = W1; dst = W1t; K = DIM; N = HID;
    n = gid & 2047; kc = (gid >> 11) & 15; e = gid >> 15;
  } else {              // W2: K=2048, N=512
    gid -= 524288u;
    src = W2; dst = W2t; K = HID; N = DIM;
    n = gid & 511; kc = (gid >> 9) & 63; e = gid >> 15;
  }
  const float* sp = src + ((size_t)e * K + kc * 32) * N + n;
  union { ushort_t u[32]; uint4 q[4]; } o;
#pragma unroll
  for (int j = 0; j < 32; j++) o.u[j] = f2b(sp[(size_t)j * N]);
  ushort_t* dp = dst + ((size_t)e * N + n) * K + kc * 32;
#pragma unroll
  for (int i = 0; i < 4; i++) *(uint4*)(dp + i * 8) = o.q[i];
}

// ---------------- router: logits, top-2, softmax, slot assignment -----------
__global__ __launch_bounds__(256) void router_k(
    const float* __restrict__ x, const float* __restrict__ Wg,
    ushort_t* __restrict__ xbf, int* __restrict__ counts,
    int* __restrict__ ltok, float* __restrict__ lw,
    float* __restrict__ s1, float* __restrict__ s2, float* __restrict__ out) {
  int t = threadIdx.x;
  {  // zero out (4MB over 64 blocks)
    float4 z = {0.f, 0.f, 0.f, 0.f};
    float4* o4 = (float4*)out + blockIdx.x * 4096 + t;
#pragma unroll
    for (int i = 0; i < 16; i++) o4[i * 256] = z;
  }
  {  // zero s1/s2
    int idx = blockIdx.x * 256 + t;
    if (idx < NROWS) { s1[idx] = 0.f; s2[idx] = 0.f; }
  }

  __shared__ float xs[4][512];
  __shared__ float lg[4][16];
  __shared__ int lcnt[NEXP];
  __shared__ int ltoks[NEXP][64];
  __shared__ float lws[NEXP][64];
  __shared__ int base_s[NEXP];

  if (t < NEXP) lcnt[t] = 0;
  __syncthreads();

  int lane = t & 63, w = t >> 6;
  int dq = lane >> 2, e4 = lane & 3;
  const float* wgp = Wg + dq * NEXP + e4 * 4;

  for (int it = 0; it < 8; it++) {
    int tok = blockIdx.x * 32 + w * 8 + it;
    const float* xr = x + (size_t)tok * DIM + lane * 8;
    float4 xa = *(const float4*)xr;
    float4 xb = *(const float4*)(xr + 4);
    union { ushort_t u[8]; uint4 v; } pk;
    pk.u[0] = f2b(xa.x); pk.u[1] = f2b(xa.y); pk.u[2] = f2b(xa.z); pk.u[3] = f2b(xa.w);
    pk.u[4] = f2b(xb.x); pk.u[5] = f2b(xb.y); pk.u[6] = f2b(xb.z); pk.u[7] = f2b(xb.w);
    *(uint4*)(xbf + (size_t)tok * DIM + lane * 8) = pk.v;
    *(float4*)&xs[w][lane * 8] = xa;
    *(float4*)&xs[w][lane * 8 + 4] = xb;

    float4 a = {0.f, 0.f, 0.f, 0.f};
#pragma unroll
    for (int kk = 0; kk < 32; kk++) {
      float xv = xs[w][kk * 16 + dq];
      float4 g = *(const float4*)(wgp + kk * 16 * NEXP);
      a.x += xv * g.x; a.y += xv * g.y; a.z += xv * g.z; a.w += xv * g.w;
    }
#pragma unroll
    for (int off = 32; off >= 4; off >>= 1) {
      a.x += __shfl_down(a.x, off);
      a.y += __shfl_down(a.y, off);
      a.z += __shfl_down(a.z, off);
      a.w += __shfl_down(a.w, off);
    }
    if (lane < 4) *(float4*)&lg[w][lane * 4] = a;
    if (lane == 0) {
      int i0 = 0;
      float v0 = lg[w][0];
#pragma unroll
      for (int e = 1; e < NEXP; e++)
        if (lg[w][e] > v0) { v0 = lg[w][e]; i0 = e; }
      int i1 = -1;
      float v1 = -3.4e38f;
#pragma unroll
      for (int e = 0; e < NEXP; e++)
        if (e != i0 && lg[w][e] > v1) { v1 = lg[w][e]; i1 = e; }
      float ex = __expf(v1 - v0);
      float w0 = 1.f / (1.f + ex);
      int p0 = atomicAdd(&lcnt[i0], 1);
      ltoks[i0][p0] = tok;
      lws[i0][p0] = w0;
      int p1 = atomicAdd(&lcnt[i1], 1);
      ltoks[i1][p1] = tok;
      lws[i1][p1] = ex / (1.f + ex);
    }
  }
  __syncthreads();
  if (t < NEXP) base_s[t] = atomicAdd(&counts[t], lcnt[t]);
  __syncthreads();
  int e = t >> 4, i0 = t & 15;
  int n = lcnt[e], b = base_s[e];
  for (int i = i0; i < n; i += 16) {
    int slot = b + i;
    if (slot < CAP) {
      ltok[e * CAP + slot] = ltoks[e][i];
      lw[e * CAP + slot] = lws[e][i];
    }
  }
}

// ---------------- GEMM1: h = silu(x @ W1 + b1), pipelined LDS-A -------------
// W1t: [E][H][D] bf16 (k=D contiguous). BK=64, 8 stages, prefetch A+B.
__global__ __launch_bounds__(256) void ffn1_k(
    const ushort_t* __restrict__ W1t, const float* __restrict__ b1,
    const int* __restrict__ counts, const int* __restrict__ ltok,
    const ushort_t* __restrict__ xbf, ushort_t* __restrict__ hbuf,
    float* __restrict__ s1, float* __restrict__ s2) {
  int e = blockIdx.x / NTPE, mt = blockIdx.x % NTPE;
  int cnt = counts[e];
  if (cnt - mt * 64 <= 0) return;
  int row0 = e * CAP + mt * 64;
  int h0 = blockIdx.y * 128;

  __shared__ __align__(16) ushort_t As[64 * 72];

  int t = threadIdx.x;
  int lane = t & 63, wave = t >> 6;
  int quad = lane >> 4, l16 = lane & 15;

  int sr = t >> 2, sp = t & 3;
  int stok = (mt * 64 + sr < cnt) ? ltok[row0 + sr] : 0;
  const ushort_t* sx = xbf + (size_t)stok * DIM + sp * 8;

  int ncol = h0 + wave * 32 + l16;
  const ushort_t* bb = W1t + ((size_t)e * HID + ncol) * DIM + quad * 8;

  f32x4 acc[4][2];
#pragma unroll
  for (int a = 0; a < 4; a++)
#pragma unroll
    for (int b = 0; b < 2; b++) acc[a][b] = {0.f, 0.f, 0.f, 0.f};

  uint4 a0 = *(const uint4*)(sx);
  uint4 a1 = *(const uint4*)(sx + 32);
  bf16x8 bc[2][2];
  bc[0][0] = *(const bf16x8*)(bb);
  bc[0][1] = *(const bf16x8*)(bb + (size_t)16 * DIM);
  bc[1][0] = *(const bf16x8*)(bb + 32);
  bc[1][1] = *(const bf16x8*)(bb + (size_t)16 * DIM + 32);

#pragma unroll
  for (int ks = 0; ks < 8; ks++) {
    __syncthreads();
    *(uint4*)(&As[sr * 72 + sp * 8]) = a0;
    *(uint4*)(&As[sr * 72 + 32 + sp * 8]) = a1;
    __syncthreads();
    bf16x8 bn[2][2];
    if (ks < 7) {
      int kc = (ks + 1) * 64;
      a0 = *(const uint4*)(sx + kc);
      a1 = *(const uint4*)(sx + kc + 32);
      bn[0][0] = *(const bf16x8*)(bb + kc);
      bn[0][1] = *(const bf16x8*)(bb + (size_t)16 * DIM + kc);
      bn[1][0] = *(const bf16x8*)(bb + kc + 32);
      bn[1][1] = *(const bf16x8*)(bb + (size_t)16 * DIM + kc + 32);
    }
#pragma unroll
    for (int kk = 0; kk < 2; kk++) {
      bf16x8 af[4];
#pragma unroll
      for (int mb = 0; mb < 4; mb++)
        af[mb] = *(const bf16x8*)(&As[(mb * 16 + l16) * 72 + kk * 32 + quad * 8]);
#pragma unroll
      for (int mb = 0; mb < 4; mb++) {
        acc[mb][0] = __builtin_amdgcn_mfma_f32_16x16x32_bf16(af[mb], bc[kk][0], acc[mb][0], 0, 0, 0);
        acc[mb][1] = __builtin_amdgcn_mfma_f32_16x16x32_bf16(af[mb], bc[kk][1], acc[mb][1], 0, 0, 0);
      }
    }
    if (ks < 7) {
      bc[0][0] = bn[0][0]; bc[0][1] = bn[0][1];
      bc[1][0] = bn[1][0]; bc[1][1] = bn[1][1];
    }
  }

  float bia0 = b1[e * HID + ncol];
  float bia1 = b1[e * HID + ncol + 16];
#pragma unroll
  for (int mb = 0; mb < 4; mb++) {
#pragma unroll
    for (int i = 0; i < 4; i++) {
      int m = mb * 16 + quad * 4 + i;
      size_t rowg = (size_t)(row0 + m);
      float v0 = acc[mb][0][i] + bia0;
      v0 = v0 / (1.f + __expf(-v0));
      float v1 = acc[mb][1][i] + bia1;
      v1 = v1 / (1.f + __expf(-v1));
      hbuf[rowg * HID + ncol] = f2b(v0);
      hbuf[rowg * HID + ncol + 16] = f2b(v1);
      float ps = v0 + v1, qs = v0 * v0 + v1 * v1;
      ps += __shfl_down(ps, 8); qs += __shfl_down(qs, 8);
      ps += __shfl_down(ps, 4); qs += __shfl_down(qs, 4);
      ps += __shfl_down(ps, 2); qs += __shfl_down(qs, 2);
      ps += __shfl_down(ps, 1); qs += __shfl_down(qs, 1);
      if (l16 == 0) {
        atomicAdd(&s1[rowg], ps);
        atomicAdd(&s2[rowg], qs);
      }
    }
  }
}

// ---------------- normalize hbuf rows in place (LayerNorm) ------------------
__global__ __launch_bounds__(256) void norm_k(
    const int* __restrict__ counts, const float* __restrict__ s1,
    const float* __restrict__ s2, const float* __restrict__ lng,
    const float* __restrict__ lnb, ushort_t* __restrict__ hbuf) {
  int row = blockIdx.x;
  int e = row / CAP;
  if ((row % CAP) >= counts[e]) return;
  float mu = s1[row] * (1.f / HID);
  float var = s2[row] * (1.f / HID) - mu * mu;
  float rs = rsqrtf(var + 1e-5f);
  int t = threadIdx.x;
  ushort_t* hp = hbuf + (size_t)row * HID + t * 8;
  const float* gp = lng + (size_t)e * HID + t * 8;
  const float* cp = lnb + (size_t)e * HID + t * 8;
  union { uint4 v; ushort_t u[8]; } hv;
  hv.v = *(const uint4*)hp;
  float4 g0 = *(const float4*)gp;
  float4 g1 = *(const float4*)(gp + 4);
  float4 c0 = *(const float4*)cp;
  float4 c1 = *(const float4*)(cp + 4);
  float gs[8] = {g0.x, g0.y, g0.z, g0.w, g1.x, g1.y, g1.z, g1.w};
  float cs[8] = {c0.x, c0.y, c0.z, c0.w, c1.x, c1.y, c1.z, c1.w};
  union { ushort_t u[8]; uint4 v; } pk;
#pragma unroll
  for (int j = 0; j < 8; j++) {
    float f = (b2f(hv.u[j]) - mu) * rs;
    pk.u[j] = f2b(f * gs[j] + cs[j]);
  }
  *(uint4*)hp = pk.v;
}

// ---------------- GEMM2: out[t] += w * (hn @ W2 + b2), pipelined LDS-A ------
// W2t: [E][D][H] bf16 (k=H contiguous). K split in 4 x 512; BK=64, 8 stages.
__global__ __launch_bounds__(256) void ffn2_k(
    const ushort_t* __restrict__ W2t, const float* __restrict__ b2,
    const int* __restrict__ counts, const int* __restrict__ ltok,
    const float* __restrict__ lw, const ushort_t* __restrict__ hbuf,
    float* __restrict__ out) {
  int e = blockIdx.x / NTPE, mt = blockIdx.x % NTPE;
  int cnt = counts[e];
  int valid = cnt - mt * 64;
  if (valid <= 0) return;
  valid = valid > 64 ? 64 : valid;
  int row0 = e * CAP + mt * 64;
  int n0 = blockIdx.y * 128;
  int kbeg = blockIdx.z * (HID / 4);

  __shared__ __align__(16) ushort_t As[64 * 72];

  int t = threadIdx.x;
  int lane = t & 63, wave = t >> 6;
  int quad = lane >> 4, l16 = lane & 15;

  int sr = t >> 2, sp = t & 3;
  const ushort_t* hr = hbuf + (size_t)(row0 + sr) * HID + kbeg + sp * 8;

  int ncol = n0 + wave * 32 + l16;
  const ushort_t* bb = W2t + ((size_t)e * DIM + ncol) * HID + kbeg + quad * 8;

  f32x4 acc[4][2];
#pragma unroll
  for (int a = 0; a < 4; a++)
#pragma unroll
    for (int b = 0; b < 2; b++) acc[a][b] = {0.f, 0.f, 0.f, 0.f};

  uint4 a0 = *(const uint4*)(hr);
  uint4 a1 = *(const uint4*)(hr + 32);
  bf16x8 bc[2][2];
  bc[0][0] = *(const bf16x8*)(bb);
  bc[0][1] = *(const bf16x8*)(bb + (size_t)16 * HID);
  bc[1][0] = *(const bf16x8*)(bb + 32);
  bc[1][1] = *(const bf16x8*)(bb + (size_t)16 * HID + 32);

#pragma unroll
  for (int ks = 0; ks < 8; ks++) {
    __syncthreads();
    *(uint4*)(&As[sr * 72 + sp * 8]) = a0;
    *(uint4*)(&As[sr * 72 + 32 + sp * 8]) = a1;
    __syncthreads();
    bf16x8 bn[2][2];
    if (ks < 7) {
      int kc = (ks + 1) * 64;
      a0 = *(const uint4*)(hr + kc);
      a1 = *(const uint4*)(hr + kc + 32);
      bn[0][0] = *(const bf16x8*)(bb + kc);
      bn[0][1] = *(const bf16x8*)(bb + (size_t)16 * HID + kc);
      bn[1][0] = *(const bf16x8*)(bb + kc + 32);
      bn[1][1] = *(const bf16x8*)(bb + (size_t)16 * HID + kc + 32);
    }
#pragma unroll
    for (int kk = 0; kk < 2; kk++) {
      bf16x8 af[4];
#pragma unroll
      for (int mb = 0; mb < 4; mb++)
        af[mb] = *(const bf16x8*)(&As[(mb * 16 + l16) * 72 + kk * 32 + quad * 8]);
#pragma unroll
      for (int mb = 0; mb < 4; mb++) {
        acc[mb][0] = __builtin_amdgcn_mfma_f32_16x16x32_bf16(af[mb], bc[kk][0], acc[mb][0], 0, 0, 0);
        acc[mb][1] = __builtin_amdgcn_mfma_f32_16x16x32_bf16(af[mb], bc[kk][1], acc[mb][1], 0, 0, 0);
      }
    }
    if (ks < 7) {
      bc[0][0] = bn[0][0]; bc[0][1] = bn[0][1];
      bc[1][0] = bn[1][0]; bc[1][1] = bn[1][1];
    }
  }

  bool addb = (blockIdx.z == 0);
#pragma unroll
  for (int mb = 0; mb < 4; mb++) {
#pragma unroll
    for (int i = 0; i < 4; i++) {
      int m = mb * 16 + quad * 4 + i;
      if (m < valid) {
        int tok = ltok[row0 + m];
        float w = lw[row0 + m];
#pragma unroll
        for (int nb = 0; nb < 2; nb++) {
          int n = ncol + nb * 16;
          float v = acc[mb][nb][i] + (addb ? b2[e * DIM + n] : 0.f);
          atomicAdd(out + (size_t)tok * DIM + n, w * v);
        }
      }
    }
  }
}

extern "C" void kernel_launch(void* const* d_in, const int* in_sizes, int n_in,
                              void* d_out, int out_size, void* d_ws, size_t ws_size,
                              hipStream_t stream) {
  const float* x = (const float*)d_in[0];
  const float* Wg = (const float*)d_in[1];
  const float* W1 = (const float*)d_in[2];
  const float* b1 = (const float*)d_in[3];
  const float* lng = (const float*)d_in[4];
  const float* lnb = (const float*)d_in[5];
  const float* W2 = (const float*)d_in[6];
  const float* b2 = (const float*)d_in[7];
  float* out = (float*)d_out;

  char* ws = (char*)d_ws;
  int* counts = (int*)(ws + OFF_CNT);
  int* ltok = (int*)(ws + OFF_LTOK);
  float* lw = (float*)(ws + OFF_LW);
  float* s1 = (float*)(ws + OFF_S1);
  float* s2 = (float*)(ws + OFF_S2);
  ushort_t* xbf = (ushort_t*)(ws + OFF_XBF);
  ushort_t* hbuf = (ushort_t*)(ws + OFF_H);
  ushort_t* W1t = (ushort_t*)(ws + OFF_W1T);
  ushort_t* W2t = (ushort_t*)(ws + OFF_W2T);

  wconv_k<<<4096, 256, 0, stream>>>(W1, W2, W1t, W2t, counts);
  router_k<<<64, 256, 0, stream>>>(x, Wg, xbf, counts, ltok, lw, s1, s2, out);
  ffn1_k<<<dim3(MTILES, HID / 128), 256, 0, stream>>>(W1t, b1, counts, ltok, xbf, hbuf, s1, s2);
  norm_k<<<NROWS, 256, 0, stream>>>(counts, s1, s2, lng, lnb, hbuf);
  ffn2_k<<<dim3(MTILES, DIM / 128, 4), 256, 0, stream>>>(W2t, b2, counts, ltok, lw, hbuf, out);
}